// Round 4
// baseline (362.223 us; speedup 1.0000x reference)
//
#include <hip/hip_runtime.h>
#include <hip/hip_bf16.h>
#include <math.h>

#define N_ROI 512
#define N_POS 128
#define NUM_CLS 81
#define KDIM 12544          // 256 ch * 7 * 7
#define HID 1024

typedef __bf16 bf16x8 __attribute__((ext_vector_type(8)));
typedef __bf16 bf16x4 __attribute__((ext_vector_type(4)));
typedef float f32x4 __attribute__((ext_vector_type(4)));

__device__ inline void gload16(const void* g, void* lds) {
  __builtin_amdgcn_global_load_lds(
      (const __attribute__((address_space(1))) void*)g,
      (__attribute__((address_space(3))) void*)lds, 16, 0, 0);
}

// ---------------------------------------------------------------------------
// ROI align, restructured: grid (512 ROIs, 7 slabs). Per-ROI separable
// geometry (14 x-samples, 14 y-samples, with byte offsets premultiplied)
// computed once into LDS by 28 threads. Then 256 threads sweep flattened
// (channel,cell) outputs: idx = slab*1792 + i*256 + t. Corner loads use a
// wave-uniform SGPR base + 32-bit voffset (c*HW*4 + by + bx).
// ---------------------------------------------------------------------------
__global__ __launch_bounds__(256) void roi_align_kernel(
    const float* __restrict__ P2, const float* __restrict__ P3,
    const float* __restrict__ P4, const float* __restrict__ P5,
    const float* __restrict__ rois, __bf16* __restrict__ xout) {
  int n = blockIdx.x;
  int t = threadIdx.x;

  __shared__ int2   gxi[14];   // {x0*4, x1*4}
  __shared__ float2 gxf[14];   // {lx, vx}
  __shared__ int2   gyi[14];   // {y0*W*4, y1*W*4}
  __shared__ float2 gyf[14];   // {ly, vy}
  __shared__ int    s_lvl, s_HWb;

  float rx1 = rois[n * 4 + 0], ry1 = rois[n * 4 + 1];
  float rx2 = rois[n * 4 + 2], ry2 = rois[n * 4 + 3];
  float area = (rx2 - rx1 + 1.0f) * (ry2 - ry1 + 1.0f);
  float lf = floorf(4.0f + log2f(sqrtf(area) / 224.0f));
  lf = fminf(fmaxf(lf, 2.0f), 5.0f);
  int lvl = (int)lf - 2;

  const float scales[4] = {0.25f, 0.125f, 0.0625f, 0.03125f};
  const int   Hs[4] = {200, 100, 50, 25};
  const int   Ws[4] = {256, 128, 64, 32};
  float sc = scales[lvl];
  int H = Hs[lvl], W = Ws[lvl];

  float bx1 = rx1 * sc, by1 = ry1 * sc;
  float bw = fmaxf(rx2 * sc - bx1, 1.0f) * (1.0f / 7.0f);
  float bh = fmaxf(ry2 * sc - by1, 1.0f) * (1.0f / 7.0f);

  if (t < 14) {  // x geometry
    int i = t >> 1, j = t & 1;
    float g = (float)i + 0.25f + 0.5f * (float)j;
    float px = bx1 + g * bw;
    float vx = (px > -1.0f && px < (float)W) ? 1.0f : 0.0f;
    float xx = fminf(fmaxf(px, 0.0f), (float)(W - 1));
    float x0f = floorf(xx);
    int x0 = (int)x0f;
    int x1 = min(x0 + 1, W - 1);
    gxi[t] = make_int2(x0 * 4, x1 * 4);
    gxf[t] = make_float2(xx - x0f, vx);
    if (t == 0) { s_lvl = lvl; s_HWb = H * W * 4; }
  } else if (t >= 64 && t < 78) {  // y geometry (second wave)
    int s = t - 64;
    int i = s >> 1, j = s & 1;
    float g = (float)i + 0.25f + 0.5f * (float)j;
    float py = by1 + g * bh;
    float vy = (py > -1.0f && py < (float)H) ? 1.0f : 0.0f;
    float yy = fminf(fmaxf(py, 0.0f), (float)(H - 1));
    float y0f = floorf(yy);
    int y0 = (int)y0f;
    int y1 = min(y0 + 1, H - 1);
    gyi[s] = make_int2(y0 * W * 4, y1 * W * 4);
    gyf[s] = make_float2(yy - y0f, vy);
  }
  __syncthreads();

  // wave-uniform scalar base pointer
  int lvl_s = __builtin_amdgcn_readfirstlane(s_lvl);
  const char* base = (const char*)(lvl_s == 0 ? P2 : lvl_s == 1 ? P3
                                   : lvl_s == 2 ? P4 : P5);
  int HWb = s_HWb;

  int idx0 = blockIdx.y * 1792 + t;
  __bf16* outn = xout + (size_t)n * KDIM;

#pragma unroll
  for (int i = 0; i < 7; ++i) {
    int idx = idx0 + i * 256;
    int c = (idx * 42800) >> 21;        // idx / 49  (valid for idx < 16384)
    int cell = idx - c * 49;
    int oh = (cell * 37) >> 8;          // cell / 7
    int ow = cell - oh * 7;

    int4 xi = *(const int4*)&gxi[2 * ow];     // bx0a,bx1a,bx0b,bx1b
    float4 xf = *(const float4*)&gxf[2 * ow]; // lxa,vxa,lxb,vxb
    int4 yi = *(const int4*)&gyi[2 * oh];
    float4 yf = *(const float4*)&gyf[2 * oh];

    int cb = c * HWb;
    float acc = 0.0f;
#pragma unroll
    for (int sy = 0; sy < 2; ++sy) {
      int by0 = sy ? yi.z : yi.x;
      int by1 = sy ? yi.w : yi.y;
      float ly = sy ? yf.z : yf.x;
      float vy = sy ? yf.w : yf.y;
#pragma unroll
      for (int sx = 0; sx < 2; ++sx) {
        int bx0 = sx ? xi.z : xi.x;
        int bx1 = sx ? xi.w : xi.y;
        float lx = sx ? xf.z : xf.x;
        float v = vy * (sx ? xf.w : xf.y);
        float f00 = *(const float*)(base + (cb + by0 + bx0));
        float f01 = *(const float*)(base + (cb + by0 + bx1));
        float f10 = *(const float*)(base + (cb + by1 + bx0));
        float f11 = *(const float*)(base + (cb + by1 + bx1));
        float fx0 = f00 + lx * (f01 - f00);
        float fx1 = f10 + lx * (f11 - f10);
        acc += (fx0 + ly * (fx1 - fx0)) * v;
      }
    }
    outn[idx] = (__bf16)(acc * 0.25f);
  }
}

// ---------------------------------------------------------------------------
// 64x64-tile transpose + fp32->bf16: src [R][C] -> dst [C][R].
// float4 reads; 16B bf16x8 stores.
// ---------------------------------------------------------------------------
__global__ __launch_bounds__(256) void transpose_to_bf16_64(
    const float* __restrict__ src, __bf16* __restrict__ dst, int R, int C) {
  __shared__ float tile[64][65];
  int t = threadIdx.x;
  int bc = blockIdx.x * 64, br = blockIdx.y * 64;
  int rr = t >> 4, c4 = (t & 15) * 4;
#pragma unroll
  for (int p = 0; p < 4; ++p) {
    int r = p * 16 + rr;
    f32x4 v = *(const f32x4*)&src[(size_t)(br + r) * C + bc + c4];
    tile[r][c4] = v.x; tile[r][c4 + 1] = v.y;
    tile[r][c4 + 2] = v.z; tile[r][c4 + 3] = v.w;
  }
  __syncthreads();
#pragma unroll
  for (int p = 0; p < 2; ++p) {
    int group = t + 256 * p;        // 0..511
    int c = group >> 3;
    int r0 = (group & 7) * 8;
    bf16x8 o;
#pragma unroll
    for (int j = 0; j < 8; ++j) o[j] = (__bf16)tile[r0 + j][c];
    *(bf16x8*)&dst[(size_t)(bc + c) * R + br + r0] = o;
  }
}

// ---------------------------------------------------------------------------
// Wcls [1024][81] fp32 -> WcT [128][1024] bf16 (rows 81..127 zero). grid(16,2)
// ---------------------------------------------------------------------------
__global__ __launch_bounds__(256) void transpose_pad_cls(
    const float* __restrict__ Wcls, __bf16* __restrict__ WcT) {
  __shared__ float tile[64][65];
  int t = threadIdx.x;
  int bk = blockIdx.x * 64;
  int bj = blockIdx.y * 64;
  int rr = t >> 4, c4 = (t & 15) * 4;
#pragma unroll
  for (int p = 0; p < 4; ++p) {
    int k = bk + p * 16 + rr;
#pragma unroll
    for (int i = 0; i < 4; ++i) {
      int j = bj + c4 + i;
      tile[p * 16 + rr][c4 + i] =
          (j < NUM_CLS) ? Wcls[(size_t)k * NUM_CLS + j] : 0.0f;
    }
  }
  __syncthreads();
#pragma unroll
  for (int p = 0; p < 4; ++p) {
    int c = p * 16 + rr;
    int r4 = c4;
    bf16x4 o = {(__bf16)tile[r4][c], (__bf16)tile[r4 + 1][c],
                (__bf16)tile[r4 + 2][c], (__bf16)tile[r4 + 3][c]};
    *(bf16x4*)&WcT[(size_t)(bj + c) * 1024 + bk + r4] = o;
  }
}

// ---------------------------------------------------------------------------
// m97-style bf16 MFMA GEMM with split-K partials. Block tile 128x128, BK=32,
// 4 waves x (64x64). global_load_lds width=16 with chunk swizzle.
// ---------------------------------------------------------------------------
__global__ __launch_bounds__(256, 2) void mfma_gemm128(
    const __bf16* __restrict__ A, const __bf16* __restrict__ Bt,
    float* __restrict__ part, int M, int N, int K, int chunk) {
  __shared__ __align__(16) unsigned char smem[16384];
  unsigned char* As = smem;
  unsigned char* Bs = smem + 8192;

  int t = threadIdx.x;
  int wave = t >> 6;
  int lane = t & 63;
  int fr = lane & 15, q = lane >> 4;
  int bm = blockIdx.y * 128, bn = blockIdx.x * 128;
  int wm = (wave >> 1) * 64, wn = (wave & 1) * 64;

  int kbeg = blockIdx.z * chunk;
  int kend = min(K, kbeg + chunk);

  int qsrc = ((t & 3) - ((t >> 3) & 3)) & 3;
  const __bf16* a0 = A + (size_t)(bm + (t >> 2)) * K + kbeg + qsrc * 8;
  const __bf16* a1 = a0 + (size_t)64 * K;
  const __bf16* b0 = Bt + (size_t)(bn + (t >> 2)) * K + kbeg + qsrc * 8;
  const __bf16* b1 = b0 + (size_t)64 * K;
  unsigned char* AsW = As + wave * 1024;
  unsigned char* BsW = Bs + wave * 1024;

  int sA = ((q + (fr >> 1)) & 3) * 16;

  f32x4 acc[4][4];
#pragma unroll
  for (int i = 0; i < 4; ++i)
#pragma unroll
    for (int j = 0; j < 4; ++j) acc[i][j] = (f32x4){0.f, 0.f, 0.f, 0.f};

  for (int k0 = kbeg; k0 < kend; k0 += 32) {
    __syncthreads();
    gload16(a0, AsW);
    gload16(a1, AsW + 4096);
    gload16(b0, BsW);
    gload16(b1, BsW + 4096);
    a0 += 32; a1 += 32; b0 += 32; b1 += 32;
    __syncthreads();

    bf16x8 af[4], bfr[4];
#pragma unroll
    for (int i = 0; i < 4; ++i)
      af[i] = *(const bf16x8*)(As + (wm + 16 * i + fr) * 64 + sA);
#pragma unroll
    for (int j = 0; j < 4; ++j)
      bfr[j] = *(const bf16x8*)(Bs + (wn + 16 * j + fr) * 64 + sA);
#pragma unroll
    for (int i = 0; i < 4; ++i)
#pragma unroll
      for (int j = 0; j < 4; ++j)
        acc[i][j] = __builtin_amdgcn_mfma_f32_16x16x32_bf16(af[i], bfr[j],
                                                            acc[i][j], 0, 0, 0);
  }

  float* P = part + (size_t)blockIdx.z * M * N;
#pragma unroll
  for (int i = 0; i < 4; ++i) {
#pragma unroll
    for (int j = 0; j < 4; ++j) {
      int row0 = bm + wm + 16 * i + q * 4;
      int col = bn + wn + 16 * j + fr;
#pragma unroll
      for (int r = 0; r < 4; ++r)
        P[(size_t)(row0 + r) * N + col] = acc[i][j][r];
    }
  }
}

// ---------------------------------------------------------------------------
// out = act(sum_z part[z] + bias); optional fp32 and bf16 outputs.
// ---------------------------------------------------------------------------
__global__ __launch_bounds__(256) void reduce_kernel(
    const float* __restrict__ part, int S, int MN, int Nmask,
    const float* __restrict__ bias, int bias_n, int relu,
    float* __restrict__ outf, __bf16* __restrict__ outb) {
  int i4 = (blockIdx.x * 256 + threadIdx.x) * 4;
  if (i4 >= MN) return;
  f32x4 s = {0.f, 0.f, 0.f, 0.f};
  for (int z = 0; z < S; ++z) {
    f32x4 v = *(const f32x4*)&part[(size_t)z * MN + i4];
    s.x += v.x; s.y += v.y; s.z += v.z; s.w += v.w;
  }
  int col = i4 & Nmask;
  float r[4] = {s.x, s.y, s.z, s.w};
#pragma unroll
  for (int j = 0; j < 4; ++j) {
    float b = (col + j < bias_n) ? bias[col + j] : 0.0f;
    float v = r[j] + b;
    if (relu) v = fmaxf(v, 0.0f);
    r[j] = v;
  }
  if (outf) {
    f32x4 o = {r[0], r[1], r[2], r[3]};
    *(f32x4*)&outf[i4] = o;
  }
  if (outb) {
    bf16x4 o = {(__bf16)r[0], (__bf16)r[1], (__bf16)r[2], (__bf16)r[3]};
    *(bf16x4*)&outb[i4] = o;
  }
}

// ---------------------------------------------------------------------------
__global__ __launch_bounds__(256) void loc_head_kernel(
    const float* __restrict__ h2, const float* __restrict__ Wloc,
    const float* __restrict__ bloc, const int* __restrict__ label,
    float* __restrict__ loct) {
  int n = blockIdx.x;
  int d = threadIdx.x >> 6;
  int lane = threadIdx.x & 63;
  int lab = label[n];
  const float* h = h2 + (size_t)n * HID;
  const float* w = Wloc + (size_t)lab * 4 + d;
  float s = 0.0f;
#pragma unroll
  for (int i = 0; i < 16; ++i) {
    int k = lane + i * 64;
    s += h[k] * w[(size_t)k * (NUM_CLS * 4)];
  }
#pragma unroll
  for (int off = 32; off > 0; off >>= 1) s += __shfl_down(s, off);
  if (lane == 0) loct[n * 4 + d] = s + bloc[lab * 4 + d];
}

// ---------------------------------------------------------------------------
__global__ __launch_bounds__(512) void loss_kernel(
    const float* __restrict__ logits, const int* __restrict__ label,
    const float* __restrict__ loct, const float* __restrict__ loc,
    float* __restrict__ out) {
  int t = threadIdx.x;
  const float* row = logits + (size_t)t * 128;
  float m = -1e30f;
  for (int j = 0; j < NUM_CLS; ++j) m = fmaxf(m, row[j]);
  float se = 0.0f;
  for (int j = 0; j < NUM_CLS; ++j) se += expf(row[j] - m);
  float cl = (m + logf(se)) - row[label[t]];

  float a = fabsf(loct[t] - loc[t]);
  float bl = (a < 1.0f) ? 0.5f * a * a : a - 0.5f;

  float v = cl + bl;
#pragma unroll
  for (int off = 32; off > 0; off >>= 1) v += __shfl_down(v, off);

  __shared__ float red[8];
  if ((t & 63) == 0) red[t >> 6] = v;
  __syncthreads();
  if (t == 0) {
    float tot = 0.0f;
    for (int i = 0; i < 8; ++i) tot += red[i];
    out[0] = tot * (1.0f / (float)N_ROI);
  }
}

// ---------------------------------------------------------------------------
extern "C" void kernel_launch(void* const* d_in, const int* in_sizes, int n_in,
                              void* d_out, int out_size, void* d_ws, size_t ws_size,
                              hipStream_t stream) {
  const float* P2   = (const float*)d_in[0];
  const float* P3   = (const float*)d_in[1];
  const float* P4   = (const float*)d_in[2];
  const float* P5   = (const float*)d_in[3];
  const float* rois = (const float*)d_in[4];
  const int*   label= (const int*)d_in[5];
  const float* loc  = (const float*)d_in[6];
  const float* W1   = (const float*)d_in[7];
  const float* b1   = (const float*)d_in[8];
  const float* W2   = (const float*)d_in[9];
  const float* b2   = (const float*)d_in[10];
  const float* Wcls = (const float*)d_in[11];
  const float* bcls = (const float*)d_in[12];
  const float* Wloc = (const float*)d_in[13];
  const float* bloc = (const float*)d_in[14];
  float* out = (float*)d_out;

  char* w = (char*)d_ws;
  __bf16* xb  = (__bf16*)w;  w += (size_t)N_ROI * KDIM * 2;
  __bf16* W1t = (__bf16*)w;  w += (size_t)KDIM * HID * 2;
  __bf16* W2t = (__bf16*)w;  w += (size_t)HID * HID * 2;
  __bf16* WcT = (__bf16*)w;  w += (size_t)128 * HID * 2;
  __bf16* h1b = (__bf16*)w;  w += (size_t)N_ROI * HID * 2;
  __bf16* h2b = (__bf16*)w;  w += (size_t)N_ROI * HID * 2;
  float*  h2f = (float*)w;   w += (size_t)N_ROI * HID * 4;
  float*  logits = (float*)w; w += (size_t)N_ROI * 128 * 4;
  float*  loct = (float*)w;  w += (size_t)N_ROI * 4;
  float*  part = (float*)w;

  transpose_to_bf16_64<<<dim3(HID / 64, KDIM / 64), 256, 0, stream>>>(W1, W1t,
                                                                      KDIM, HID);
  transpose_to_bf16_64<<<dim3(HID / 64, HID / 64), 256, 0, stream>>>(W2, W2t,
                                                                     HID, HID);
  transpose_pad_cls<<<dim3(16, 2), 256, 0, stream>>>(Wcls, WcT);
  roi_align_kernel<<<dim3(N_ROI, 7), 256, 0, stream>>>(P2, P3, P4, P5, rois,
                                                       xb);

  // FC1: [512,12544]@[12544,1024], split-K 16 (chunk 800; last 544)
  mfma_gemm128<<<dim3(HID / 128, N_ROI / 128, 16), 256, 0, stream>>>(
      xb, W1t, part, N_ROI, HID, KDIM, 800);
  reduce_kernel<<<(N_ROI * HID) / 1024, 256, 0, stream>>>(
      part, 16, N_ROI * HID, HID - 1, b1, HID, 1, nullptr, h1b);

  // FC2: [512,1024]@[1024,1024], split-K 8 (chunk 128)
  mfma_gemm128<<<dim3(HID / 128, N_ROI / 128, 8), 256, 0, stream>>>(
      h1b, W2t, part, N_ROI, HID, HID, 128);
  reduce_kernel<<<(N_ROI * HID) / 1024, 256, 0, stream>>>(
      part, 8, N_ROI * HID, HID - 1, b2, HID, 1, h2f, h2b);

  // cls head: [512,1024]@[1024,128pad], split-K 4 (chunk 256)
  mfma_gemm128<<<dim3(1, N_ROI / 128, 4), 256, 0, stream>>>(
      h2b, WcT, part, N_ROI, 128, HID, 256);
  reduce_kernel<<<(N_ROI * 128) / 1024, 256, 0, stream>>>(
      part, 4, N_ROI * 128, 127, bcls, NUM_CLS, 0, logits, nullptr);

  loc_head_kernel<<<N_POS, 256, 0, stream>>>(h2f, Wloc, bloc, label, loct);
  loss_kernel<<<1, 512, 0, stream>>>(logits, label, loct, loc, out);
}

// Round 5
// 345.107 us; speedup vs baseline: 1.0496x; 1.0496x over previous
//
#include <hip/hip_runtime.h>
#include <hip/hip_bf16.h>
#include <math.h>

#define N_ROI 512
#define N_POS 128
#define NUM_CLS 81
#define KDIM 12544          // 256 ch * 7 * 7
#define HID 1024

typedef __bf16 bf16x8 __attribute__((ext_vector_type(8)));
typedef __bf16 bf16x4 __attribute__((ext_vector_type(4)));
typedef float f32x4 __attribute__((ext_vector_type(4)));

__device__ inline void gload16(const void* g, void* lds) {
  __builtin_amdgcn_global_load_lds(
      (const __attribute__((address_space(1))) void*)g,
      (__attribute__((address_space(3))) void*)lds, 16, 0, 0);
}

__device__ inline float bilin4(const char* bc, int ya, int yb, int xa, int xb,
                               float ly, float lx) {
  float f00 = *(const float*)(bc + (ya + xa));
  float f01 = *(const float*)(bc + (ya + xb));
  float f10 = *(const float*)(bc + (yb + xa));
  float f11 = *(const float*)(bc + (yb + xb));
  float fx0 = f00 + lx * (f01 - f00);
  float fx1 = f10 + lx * (f11 - f10);
  return fx0 + ly * (fx1 - fx0);
}

// ---------------------------------------------------------------------------
// ROI align v3: grid (512 ROIs, 16 channel-groups). Block = 4 waves; each
// wave owns 4 consecutive channels (one plane at a time -> gather locality),
// lanes 0..48 = the 49 output cells. Separable geometry (14 x, 14 y samples,
// byte offsets premultiplied) computed once per block into LDS; each thread
// reads its cell's geometry ONCE (4 x ds_read_b128), then loops 4 channels
// with independent accumulators (ILP for gather latency hiding). Addresses
// are 32-bit offsets off a block-uniform base pointer.
// ---------------------------------------------------------------------------
__global__ __launch_bounds__(256) void roi_align_kernel(
    const float* __restrict__ P2, const float* __restrict__ P3,
    const float* __restrict__ P4, const float* __restrict__ P5,
    const float* __restrict__ rois, __bf16* __restrict__ xout) {
  int n = blockIdx.x;
  int t = threadIdx.x;

  __shared__ int2   gxi[14];   // {x0*4, x1*4}
  __shared__ float2 gxf[14];   // {lx, vx}
  __shared__ int2   gyi[14];   // {y0*W*4, y1*W*4}
  __shared__ float2 gyf[14];   // {ly, vy}
  __shared__ int    s_lvl, s_HWb;

  float rx1 = rois[n * 4 + 0], ry1 = rois[n * 4 + 1];
  float rx2 = rois[n * 4 + 2], ry2 = rois[n * 4 + 3];
  float area = (rx2 - rx1 + 1.0f) * (ry2 - ry1 + 1.0f);
  float lf = floorf(4.0f + log2f(sqrtf(area) / 224.0f));
  lf = fminf(fmaxf(lf, 2.0f), 5.0f);
  int lvl = (int)lf - 2;

  const float scales[4] = {0.25f, 0.125f, 0.0625f, 0.03125f};
  const int   Hs[4] = {200, 100, 50, 25};
  const int   Ws[4] = {256, 128, 64, 32};
  float sc = scales[lvl];
  int H = Hs[lvl], W = Ws[lvl];

  float bx1 = rx1 * sc, by1 = ry1 * sc;
  float bw = fmaxf(rx2 * sc - bx1, 1.0f) * (1.0f / 7.0f);
  float bh = fmaxf(ry2 * sc - by1, 1.0f) * (1.0f / 7.0f);

  if (t < 14) {  // x geometry
    int i = t >> 1, j = t & 1;
    float g = (float)i + 0.25f + 0.5f * (float)j;
    float px = bx1 + g * bw;
    float vx = (px > -1.0f && px < (float)W) ? 1.0f : 0.0f;
    float xx = fminf(fmaxf(px, 0.0f), (float)(W - 1));
    float x0f = floorf(xx);
    int x0 = (int)x0f;
    int x1 = min(x0 + 1, W - 1);
    gxi[t] = make_int2(x0 * 4, x1 * 4);
    gxf[t] = make_float2(xx - x0f, vx);
    if (t == 0) { s_lvl = lvl; s_HWb = H * W * 4; }
  } else if (t >= 64 && t < 78) {  // y geometry (second wave)
    int s = t - 64;
    int i = s >> 1, j = s & 1;
    float g = (float)i + 0.25f + 0.5f * (float)j;
    float py = by1 + g * bh;
    float vy = (py > -1.0f && py < (float)H) ? 1.0f : 0.0f;
    float yy = fminf(fmaxf(py, 0.0f), (float)(H - 1));
    float y0f = floorf(yy);
    int y0 = (int)y0f;
    int y1 = min(y0 + 1, H - 1);
    gyi[s] = make_int2(y0 * W * 4, y1 * W * 4);
    gyf[s] = make_float2(yy - y0f, vy);
  }
  __syncthreads();

  int lvl_s = __builtin_amdgcn_readfirstlane(s_lvl);
  const char* base = (const char*)(lvl_s == 0 ? P2 : lvl_s == 1 ? P3
                                   : lvl_s == 2 ? P4 : P5);
  int HWb = s_HWb;

  int wave = t >> 6, lane = t & 63;
  if (lane >= 49) return;

  int oh = (lane * 37) >> 8;   // lane / 7 for lane < 49
  int ow = lane - oh * 7;

  // per-thread geometry, read once: {a,b} sample pairs in x and y
  int4   xi = *(const int4*)&gxi[2 * ow];    // x0a,x1a,x0b,x1b (bytes)
  float4 xf = *(const float4*)&gxf[2 * ow];  // lxa,vxa,lxb,vxb
  int4   yi = *(const int4*)&gyi[2 * oh];    // y0a,y1a,y0b,y1b (bytes)
  float4 yf = *(const float4*)&gyf[2 * oh];  // lya,vya,lyb,vyb

  float vaa = yf.y * xf.y, vab = yf.y * xf.w;
  float vba = yf.w * xf.y, vbb = yf.w * xf.w;

  int c0 = blockIdx.y * 16 + wave * 4;
  const char* bc = base + (size_t)c0 * HWb;
  __bf16* outp = xout + (size_t)n * KDIM + (size_t)c0 * 49 + lane;

#pragma unroll
  for (int i = 0; i < 4; ++i) {
    float sa = bilin4(bc, yi.x, yi.y, xi.x, xi.y, yf.x, xf.x) * vaa;
    float sb = bilin4(bc, yi.x, yi.y, xi.z, xi.w, yf.x, xf.z) * vab;
    float sc2 = bilin4(bc, yi.z, yi.w, xi.x, xi.y, yf.z, xf.x) * vba;
    float sd = bilin4(bc, yi.z, yi.w, xi.z, xi.w, yf.z, xf.z) * vbb;
    outp[0] = (__bf16)((sa + sb + sc2 + sd) * 0.25f);
    bc += HWb;
    outp += 49;
  }
}

// ---------------------------------------------------------------------------
// 64x64-tile transpose + fp32->bf16: src [R][C] -> dst [C][R].
// ---------------------------------------------------------------------------
__global__ __launch_bounds__(256) void transpose_to_bf16_64(
    const float* __restrict__ src, __bf16* __restrict__ dst, int R, int C) {
  __shared__ float tile[64][65];
  int t = threadIdx.x;
  int bc = blockIdx.x * 64, br = blockIdx.y * 64;
  int rr = t >> 4, c4 = (t & 15) * 4;
#pragma unroll
  for (int p = 0; p < 4; ++p) {
    int r = p * 16 + rr;
    f32x4 v = *(const f32x4*)&src[(size_t)(br + r) * C + bc + c4];
    tile[r][c4] = v.x; tile[r][c4 + 1] = v.y;
    tile[r][c4 + 2] = v.z; tile[r][c4 + 3] = v.w;
  }
  __syncthreads();
#pragma unroll
  for (int p = 0; p < 2; ++p) {
    int group = t + 256 * p;
    int c = group >> 3;
    int r0 = (group & 7) * 8;
    bf16x8 o;
#pragma unroll
    for (int j = 0; j < 8; ++j) o[j] = (__bf16)tile[r0 + j][c];
    *(bf16x8*)&dst[(size_t)(bc + c) * R + br + r0] = o;
  }
}

// ---------------------------------------------------------------------------
// Wcls [1024][81] fp32 -> WcT [128][1024] bf16 (rows 81..127 zero). grid(16,2)
// ---------------------------------------------------------------------------
__global__ __launch_bounds__(256) void transpose_pad_cls(
    const float* __restrict__ Wcls, __bf16* __restrict__ WcT) {
  __shared__ float tile[64][65];
  int t = threadIdx.x;
  int bk = blockIdx.x * 64;
  int bj = blockIdx.y * 64;
  int rr = t >> 4, c4 = (t & 15) * 4;
#pragma unroll
  for (int p = 0; p < 4; ++p) {
    int k = bk + p * 16 + rr;
#pragma unroll
    for (int i = 0; i < 4; ++i) {
      int j = bj + c4 + i;
      tile[p * 16 + rr][c4 + i] =
          (j < NUM_CLS) ? Wcls[(size_t)k * NUM_CLS + j] : 0.0f;
    }
  }
  __syncthreads();
#pragma unroll
  for (int p = 0; p < 4; ++p) {
    int c = p * 16 + rr;
    int r4 = c4;
    bf16x4 o = {(__bf16)tile[r4][c], (__bf16)tile[r4 + 1][c],
                (__bf16)tile[r4 + 2][c], (__bf16)tile[r4 + 3][c]};
    *(bf16x4*)&WcT[(size_t)(bj + c) * 1024 + bk + r4] = o;
  }
}

// ---------------------------------------------------------------------------
// m97-style bf16 MFMA GEMM with split-K partials. Block tile 128x128, BK=32,
// 4 waves x (64x64). global_load_lds width=16 with chunk swizzle.
// ---------------------------------------------------------------------------
__global__ __launch_bounds__(256, 2) void mfma_gemm128(
    const __bf16* __restrict__ A, const __bf16* __restrict__ Bt,
    float* __restrict__ part, int M, int N, int K, int chunk) {
  __shared__ __align__(16) unsigned char smem[16384];
  unsigned char* As = smem;
  unsigned char* Bs = smem + 8192;

  int t = threadIdx.x;
  int wave = t >> 6;
  int lane = t & 63;
  int fr = lane & 15, q = lane >> 4;
  int bm = blockIdx.y * 128, bn = blockIdx.x * 128;
  int wm = (wave >> 1) * 64, wn = (wave & 1) * 64;

  int kbeg = blockIdx.z * chunk;
  int kend = min(K, kbeg + chunk);

  int qsrc = ((t & 3) - ((t >> 3) & 3)) & 3;
  const __bf16* a0 = A + (size_t)(bm + (t >> 2)) * K + kbeg + qsrc * 8;
  const __bf16* a1 = a0 + (size_t)64 * K;
  const __bf16* b0 = Bt + (size_t)(bn + (t >> 2)) * K + kbeg + qsrc * 8;
  const __bf16* b1 = b0 + (size_t)64 * K;
  unsigned char* AsW = As + wave * 1024;
  unsigned char* BsW = Bs + wave * 1024;

  int sA = ((q + (fr >> 1)) & 3) * 16;

  f32x4 acc[4][4];
#pragma unroll
  for (int i = 0; i < 4; ++i)
#pragma unroll
    for (int j = 0; j < 4; ++j) acc[i][j] = (f32x4){0.f, 0.f, 0.f, 0.f};

  for (int k0 = kbeg; k0 < kend; k0 += 32) {
    __syncthreads();
    gload16(a0, AsW);
    gload16(a1, AsW + 4096);
    gload16(b0, BsW);
    gload16(b1, BsW + 4096);
    a0 += 32; a1 += 32; b0 += 32; b1 += 32;
    __syncthreads();

    bf16x8 af[4], bfr[4];
#pragma unroll
    for (int i = 0; i < 4; ++i)
      af[i] = *(const bf16x8*)(As + (wm + 16 * i + fr) * 64 + sA);
#pragma unroll
    for (int j = 0; j < 4; ++j)
      bfr[j] = *(const bf16x8*)(Bs + (wn + 16 * j + fr) * 64 + sA);
#pragma unroll
    for (int i = 0; i < 4; ++i)
#pragma unroll
      for (int j = 0; j < 4; ++j)
        acc[i][j] = __builtin_amdgcn_mfma_f32_16x16x32_bf16(af[i], bfr[j],
                                                            acc[i][j], 0, 0, 0);
  }

  float* P = part + (size_t)blockIdx.z * M * N;
#pragma unroll
  for (int i = 0; i < 4; ++i) {
#pragma unroll
    for (int j = 0; j < 4; ++j) {
      int row0 = bm + wm + 16 * i + q * 4;
      int col = bn + wn + 16 * j + fr;
#pragma unroll
      for (int r = 0; r < 4; ++r)
        P[(size_t)(row0 + r) * N + col] = acc[i][j][r];
    }
  }
}

// ---------------------------------------------------------------------------
// out = act(sum_z part[z] + bias); optional fp32 and bf16 outputs.
// ---------------------------------------------------------------------------
__global__ __launch_bounds__(256) void reduce_kernel(
    const float* __restrict__ part, int S, int MN, int Nmask,
    const float* __restrict__ bias, int bias_n, int relu,
    float* __restrict__ outf, __bf16* __restrict__ outb) {
  int i4 = (blockIdx.x * 256 + threadIdx.x) * 4;
  if (i4 >= MN) return;
  f32x4 s = {0.f, 0.f, 0.f, 0.f};
  for (int z = 0; z < S; ++z) {
    f32x4 v = *(const f32x4*)&part[(size_t)z * MN + i4];
    s.x += v.x; s.y += v.y; s.z += v.z; s.w += v.w;
  }
  int col = i4 & Nmask;
  float r[4] = {s.x, s.y, s.z, s.w};
#pragma unroll
  for (int j = 0; j < 4; ++j) {
    float b = (col + j < bias_n) ? bias[col + j] : 0.0f;
    float v = r[j] + b;
    if (relu) v = fmaxf(v, 0.0f);
    r[j] = v;
  }
  if (outf) {
    f32x4 o = {r[0], r[1], r[2], r[3]};
    *(f32x4*)&outf[i4] = o;
  }
  if (outb) {
    bf16x4 o = {(__bf16)r[0], (__bf16)r[1], (__bf16)r[2], (__bf16)r[3]};
    *(bf16x4*)&outb[i4] = o;
  }
}

// ---------------------------------------------------------------------------
__global__ __launch_bounds__(256) void loc_head_kernel(
    const float* __restrict__ h2, const float* __restrict__ Wloc,
    const float* __restrict__ bloc, const int* __restrict__ label,
    float* __restrict__ loct) {
  int n = blockIdx.x;
  int d = threadIdx.x >> 6;
  int lane = threadIdx.x & 63;
  int lab = label[n];
  const float* h = h2 + (size_t)n * HID;
  const float* w = Wloc + (size_t)lab * 4 + d;
  float s = 0.0f;
#pragma unroll
  for (int i = 0; i < 16; ++i) {
    int k = lane + i * 64;
    s += h[k] * w[(size_t)k * (NUM_CLS * 4)];
  }
#pragma unroll
  for (int off = 32; off > 0; off >>= 1) s += __shfl_down(s, off);
  if (lane == 0) loct[n * 4 + d] = s + bloc[lab * 4 + d];
}

// ---------------------------------------------------------------------------
__global__ __launch_bounds__(512) void loss_kernel(
    const float* __restrict__ logits, const int* __restrict__ label,
    const float* __restrict__ loct, const float* __restrict__ loc,
    float* __restrict__ out) {
  int t = threadIdx.x;
  const float* row = logits + (size_t)t * 128;
  float m = -1e30f;
  for (int j = 0; j < NUM_CLS; ++j) m = fmaxf(m, row[j]);
  float se = 0.0f;
  for (int j = 0; j < NUM_CLS; ++j) se += expf(row[j] - m);
  float cl = (m + logf(se)) - row[label[t]];

  float a = fabsf(loct[t] - loc[t]);
  float bl = (a < 1.0f) ? 0.5f * a * a : a - 0.5f;

  float v = cl + bl;
#pragma unroll
  for (int off = 32; off > 0; off >>= 1) v += __shfl_down(v, off);

  __shared__ float red[8];
  if ((t & 63) == 0) red[t >> 6] = v;
  __syncthreads();
  if (t == 0) {
    float tot = 0.0f;
    for (int i = 0; i < 8; ++i) tot += red[i];
    out[0] = tot * (1.0f / (float)N_ROI);
  }
}

// ---------------------------------------------------------------------------
extern "C" void kernel_launch(void* const* d_in, const int* in_sizes, int n_in,
                              void* d_out, int out_size, void* d_ws, size_t ws_size,
                              hipStream_t stream) {
  const float* P2   = (const float*)d_in[0];
  const float* P3   = (const float*)d_in[1];
  const float* P4   = (const float*)d_in[2];
  const float* P5   = (const float*)d_in[3];
  const float* rois = (const float*)d_in[4];
  const int*   label= (const int*)d_in[5];
  const float* loc  = (const float*)d_in[6];
  const float* W1   = (const float*)d_in[7];
  const float* b1   = (const float*)d_in[8];
  const float* W2   = (const float*)d_in[9];
  const float* b2   = (const float*)d_in[10];
  const float* Wcls = (const float*)d_in[11];
  const float* bcls = (const float*)d_in[12];
  const float* Wloc = (const float*)d_in[13];
  const float* bloc = (const float*)d_in[14];
  float* out = (float*)d_out;

  char* w = (char*)d_ws;
  __bf16* xb  = (__bf16*)w;  w += (size_t)N_ROI * KDIM * 2;
  __bf16* W1t = (__bf16*)w;  w += (size_t)KDIM * HID * 2;
  __bf16* W2t = (__bf16*)w;  w += (size_t)HID * HID * 2;
  __bf16* WcT = (__bf16*)w;  w += (size_t)128 * HID * 2;
  __bf16* h1b = (__bf16*)w;  w += (size_t)N_ROI * HID * 2;
  __bf16* h2b = (__bf16*)w;  w += (size_t)N_ROI * HID * 2;
  float*  h2f = (float*)w;   w += (size_t)N_ROI * HID * 4;
  float*  logits = (float*)w; w += (size_t)N_ROI * 128 * 4;
  float*  loct = (float*)w;  w += (size_t)N_ROI * 4;
  float*  part = (float*)w;

  transpose_to_bf16_64<<<dim3(HID / 64, KDIM / 64), 256, 0, stream>>>(W1, W1t,
                                                                      KDIM, HID);
  transpose_to_bf16_64<<<dim3(HID / 64, HID / 64), 256, 0, stream>>>(W2, W2t,
                                                                     HID, HID);
  transpose_pad_cls<<<dim3(16, 2), 256, 0, stream>>>(Wcls, WcT);
  roi_align_kernel<<<dim3(N_ROI, 16), 256, 0, stream>>>(P2, P3, P4, P5, rois,
                                                        xb);

  // FC1: [512,12544]@[12544,1024], split-K 16 (chunk 800; last 544)
  mfma_gemm128<<<dim3(HID / 128, N_ROI / 128, 16), 256, 0, stream>>>(
      xb, W1t, part, N_ROI, HID, KDIM, 800);
  reduce_kernel<<<(N_ROI * HID) / 1024, 256, 0, stream>>>(
      part, 16, N_ROI * HID, HID - 1, b1, HID, 1, nullptr, h1b);

  // FC2: [512,1024]@[1024,1024], split-K 8 (chunk 128)
  mfma_gemm128<<<dim3(HID / 128, N_ROI / 128, 8), 256, 0, stream>>>(
      h1b, W2t, part, N_ROI, HID, HID, 128);
  reduce_kernel<<<(N_ROI * HID) / 1024, 256, 0, stream>>>(
      part, 8, N_ROI * HID, HID - 1, b2, HID, 1, h2f, h2b);

  // cls head: [512,1024]@[1024,128pad], split-K 4 (chunk 256)
  mfma_gemm128<<<dim3(1, N_ROI / 128, 4), 256, 0, stream>>>(
      h2b, WcT, part, N_ROI, 128, HID, 256);
  reduce_kernel<<<(N_ROI * 128) / 1024, 256, 0, stream>>>(
      part, 4, N_ROI * 128, 127, bcls, NUM_CLS, 0, logits, nullptr);

  loc_head_kernel<<<N_POS, 256, 0, stream>>>(h2f, Wloc, bloc, label, loct);
  loss_kernel<<<1, 512, 0, stream>>>(logits, label, loct, loc, out);
}

// Round 6
// 292.684 us; speedup vs baseline: 1.2376x; 1.1791x over previous
//
#include <hip/hip_runtime.h>
#include <hip/hip_bf16.h>
#include <math.h>

#define N_ROI 512
#define N_POS 128
#define NUM_CLS 81
#define KDIM 12544          // 256 ch * 7 * 7
#define HID 1024

typedef __bf16 bf16x8 __attribute__((ext_vector_type(8)));
typedef __bf16 bf16x4 __attribute__((ext_vector_type(4)));
typedef float f32x4 __attribute__((ext_vector_type(4)));

__device__ inline void gload16(const void* g, void* lds) {
  __builtin_amdgcn_global_load_lds(
      (const __attribute__((address_space(1))) void*)g,
      (__attribute__((address_space(3))) void*)lds, 16, 0, 0);
}

// ---------------------------------------------------------------------------
// ROI align v4: grid (512 ROIs, 16 channel-groups), block = 4 waves, wave =
// 4 channels, lanes 0..48 = cells. Changes vs v3:
//  - x corner pair loaded as ONE float2 (8B): xa = min(x0,W-2), border clamp
//    folded into lx' = (x0>xa) ? 1 : lx  (exact, and never OOB).
//  - all 4 channels x 8 loads issued into g[4][8] BEFORE any compute ->
//    32 loads in flight (VGPR ~96), breaking the serial latency chain.
// ---------------------------------------------------------------------------
__global__ __launch_bounds__(256) void roi_align_kernel(
    const float* __restrict__ P2, const float* __restrict__ P3,
    const float* __restrict__ P4, const float* __restrict__ P5,
    const float* __restrict__ rois, __bf16* __restrict__ xout) {
  int n = blockIdx.x;
  int t = threadIdx.x;

  __shared__ int    gxo[14];   // min(x0,W-2)*4
  __shared__ float2 gxf[14];   // {lx' (border-adjusted), vx}
  __shared__ int2   gyi[14];   // {y0*W*4, y1*W*4}
  __shared__ float2 gyf[14];   // {ly, vy}
  __shared__ int    s_lvl, s_HWb;

  float rx1 = rois[n * 4 + 0], ry1 = rois[n * 4 + 1];
  float rx2 = rois[n * 4 + 2], ry2 = rois[n * 4 + 3];
  float area = (rx2 - rx1 + 1.0f) * (ry2 - ry1 + 1.0f);
  float lf = floorf(4.0f + log2f(sqrtf(area) / 224.0f));
  lf = fminf(fmaxf(lf, 2.0f), 5.0f);
  int lvl = (int)lf - 2;

  const float scales[4] = {0.25f, 0.125f, 0.0625f, 0.03125f};
  const int   Hs[4] = {200, 100, 50, 25};
  const int   Ws[4] = {256, 128, 64, 32};
  float sc = scales[lvl];
  int H = Hs[lvl], W = Ws[lvl];

  float bx1 = rx1 * sc, by1 = ry1 * sc;
  float bw = fmaxf(rx2 * sc - bx1, 1.0f) * (1.0f / 7.0f);
  float bh = fmaxf(ry2 * sc - by1, 1.0f) * (1.0f / 7.0f);

  if (t < 14) {  // x geometry
    int i = t >> 1, j = t & 1;
    float g = (float)i + 0.25f + 0.5f * (float)j;
    float px = bx1 + g * bw;
    float vx = (px > -1.0f && px < (float)W) ? 1.0f : 0.0f;
    float xx = fminf(fmaxf(px, 0.0f), (float)(W - 1));
    float x0f = floorf(xx);
    int x0 = (int)x0f;
    int xa = min(x0, W - 2);
    float lxp = (x0 > xa) ? 1.0f : (xx - x0f);
    gxo[t] = xa * 4;
    gxf[t] = make_float2(lxp, vx);
    if (t == 0) { s_lvl = lvl; s_HWb = H * W * 4; }
  } else if (t >= 64 && t < 78) {  // y geometry (second wave)
    int s = t - 64;
    int i = s >> 1, j = s & 1;
    float g = (float)i + 0.25f + 0.5f * (float)j;
    float py = by1 + g * bh;
    float vy = (py > -1.0f && py < (float)H) ? 1.0f : 0.0f;
    float yy = fminf(fmaxf(py, 0.0f), (float)(H - 1));
    float y0f = floorf(yy);
    int y0 = (int)y0f;
    int y1 = min(y0 + 1, H - 1);
    gyi[s] = make_int2(y0 * W * 4, y1 * W * 4);
    gyf[s] = make_float2(yy - y0f, vy);
  }
  __syncthreads();

  int lvl_s = __builtin_amdgcn_readfirstlane(s_lvl);
  const char* base = (const char*)(lvl_s == 0 ? P2 : lvl_s == 1 ? P3
                                   : lvl_s == 2 ? P4 : P5);
  int HWb = s_HWb;

  int wave = t >> 6, lane = t & 63;
  if (lane >= 49) return;

  int oh = (lane * 37) >> 8;   // lane / 7 for lane < 49
  int ow = lane - oh * 7;

  int2   xo = *(const int2*)&gxo[2 * ow];    // xa bytes, sx=0/1
  float4 xf = *(const float4*)&gxf[2 * ow];  // lx0,vx0,lx1,vx1
  int4   yi = *(const int4*)&gyi[2 * oh];    // y0a,y1a,y0b,y1b bytes
  float4 yf = *(const float4*)&gyf[2 * oh];  // ly0,vy0,ly1,vy1

  // combined offsets: idx = sy*4 + sx*2 + row
  int off[8];
  off[0] = yi.x + xo.x; off[1] = yi.y + xo.x;
  off[2] = yi.x + xo.y; off[3] = yi.y + xo.y;
  off[4] = yi.z + xo.x; off[5] = yi.w + xo.x;
  off[6] = yi.z + xo.y; off[7] = yi.w + xo.y;

  float w00 = yf.y * xf.y, w01 = yf.y * xf.w;  // (sy,sx) weights
  float w10 = yf.w * xf.y, w11 = yf.w * xf.w;

  int c0 = blockIdx.y * 16 + wave * 4;
  const char* bc0 = base + (size_t)c0 * HWb;

  // batch ALL loads first (32 float2 loads in flight)
  float2 g[4][8];
#pragma unroll
  for (int ch = 0; ch < 4; ++ch) {
    const char* bcc = bc0 + (size_t)ch * HWb;
#pragma unroll
    for (int l = 0; l < 8; ++l)
      g[ch][l] = *(const float2*)(bcc + off[l]);
  }

  __bf16* outp = xout + (size_t)n * KDIM + (size_t)c0 * 49 + lane;
#pragma unroll
  for (int ch = 0; ch < 4; ++ch) {
    float s = 0.0f;
    {  // sy=0, sx=0
      float fa = g[ch][0].x + xf.x * (g[ch][0].y - g[ch][0].x);
      float fb = g[ch][1].x + xf.x * (g[ch][1].y - g[ch][1].x);
      s += (fa + yf.x * (fb - fa)) * w00;
    }
    {  // sy=0, sx=1
      float fa = g[ch][2].x + xf.z * (g[ch][2].y - g[ch][2].x);
      float fb = g[ch][3].x + xf.z * (g[ch][3].y - g[ch][3].x);
      s += (fa + yf.x * (fb - fa)) * w01;
    }
    {  // sy=1, sx=0
      float fa = g[ch][4].x + xf.x * (g[ch][4].y - g[ch][4].x);
      float fb = g[ch][5].x + xf.x * (g[ch][5].y - g[ch][5].x);
      s += (fa + yf.z * (fb - fa)) * w10;
    }
    {  // sy=1, sx=1
      float fa = g[ch][6].x + xf.z * (g[ch][6].y - g[ch][6].x);
      float fb = g[ch][7].x + xf.z * (g[ch][7].y - g[ch][7].x);
      s += (fa + yf.z * (fb - fa)) * w11;
    }
    outp[ch * 49] = (__bf16)(s * 0.25f);
  }
}

// ---------------------------------------------------------------------------
// 64x64-tile transpose + fp32->bf16: src [R][C] -> dst [C][R].
// ---------------------------------------------------------------------------
__global__ __launch_bounds__(256) void transpose_to_bf16_64(
    const float* __restrict__ src, __bf16* __restrict__ dst, int R, int C) {
  __shared__ float tile[64][65];
  int t = threadIdx.x;
  int bc = blockIdx.x * 64, br = blockIdx.y * 64;
  int rr = t >> 4, c4 = (t & 15) * 4;
#pragma unroll
  for (int p = 0; p < 4; ++p) {
    int r = p * 16 + rr;
    f32x4 v = *(const f32x4*)&src[(size_t)(br + r) * C + bc + c4];
    tile[r][c4] = v.x; tile[r][c4 + 1] = v.y;
    tile[r][c4 + 2] = v.z; tile[r][c4 + 3] = v.w;
  }
  __syncthreads();
#pragma unroll
  for (int p = 0; p < 2; ++p) {
    int group = t + 256 * p;
    int c = group >> 3;
    int r0 = (group & 7) * 8;
    bf16x8 o;
#pragma unroll
    for (int j = 0; j < 8; ++j) o[j] = (__bf16)tile[r0 + j][c];
    *(bf16x8*)&dst[(size_t)(bc + c) * R + br + r0] = o;
  }
}

// ---------------------------------------------------------------------------
// Wcls [1024][81] fp32 -> WcT [128][1024] bf16 (rows 81..127 zero). grid(16,2)
// ---------------------------------------------------------------------------
__global__ __launch_bounds__(256) void transpose_pad_cls(
    const float* __restrict__ Wcls, __bf16* __restrict__ WcT) {
  __shared__ float tile[64][65];
  int t = threadIdx.x;
  int bk = blockIdx.x * 64;
  int bj = blockIdx.y * 64;
  int rr = t >> 4, c4 = (t & 15) * 4;
#pragma unroll
  for (int p = 0; p < 4; ++p) {
    int k = bk + p * 16 + rr;
#pragma unroll
    for (int i = 0; i < 4; ++i) {
      int j = bj + c4 + i;
      tile[p * 16 + rr][c4 + i] =
          (j < NUM_CLS) ? Wcls[(size_t)k * NUM_CLS + j] : 0.0f;
    }
  }
  __syncthreads();
#pragma unroll
  for (int p = 0; p < 4; ++p) {
    int c = p * 16 + rr;
    int r4 = c4;
    bf16x4 o = {(__bf16)tile[r4][c], (__bf16)tile[r4 + 1][c],
                (__bf16)tile[r4 + 2][c], (__bf16)tile[r4 + 3][c]};
    *(bf16x4*)&WcT[(size_t)(bj + c) * 1024 + bk + r4] = o;
  }
}

// ---------------------------------------------------------------------------
// m97-style bf16 MFMA GEMM with split-K partials. Block tile 128x128, BK=32,
// 4 waves x (64x64). global_load_lds width=16 with chunk swizzle.
// ---------------------------------------------------------------------------
__global__ __launch_bounds__(256, 2) void mfma_gemm128(
    const __bf16* __restrict__ A, const __bf16* __restrict__ Bt,
    float* __restrict__ part, int M, int N, int K, int chunk) {
  __shared__ __align__(16) unsigned char smem[16384];
  unsigned char* As = smem;
  unsigned char* Bs = smem + 8192;

  int t = threadIdx.x;
  int wave = t >> 6;
  int lane = t & 63;
  int fr = lane & 15, q = lane >> 4;
  int bm = blockIdx.y * 128, bn = blockIdx.x * 128;
  int wm = (wave >> 1) * 64, wn = (wave & 1) * 64;

  int kbeg = blockIdx.z * chunk;
  int kend = min(K, kbeg + chunk);

  int qsrc = ((t & 3) - ((t >> 3) & 3)) & 3;
  const __bf16* a0 = A + (size_t)(bm + (t >> 2)) * K + kbeg + qsrc * 8;
  const __bf16* a1 = a0 + (size_t)64 * K;
  const __bf16* b0 = Bt + (size_t)(bn + (t >> 2)) * K + kbeg + qsrc * 8;
  const __bf16* b1 = b0 + (size_t)64 * K;
  unsigned char* AsW = As + wave * 1024;
  unsigned char* BsW = Bs + wave * 1024;

  int sA = ((q + (fr >> 1)) & 3) * 16;

  f32x4 acc[4][4];
#pragma unroll
  for (int i = 0; i < 4; ++i)
#pragma unroll
    for (int j = 0; j < 4; ++j) acc[i][j] = (f32x4){0.f, 0.f, 0.f, 0.f};

  for (int k0 = kbeg; k0 < kend; k0 += 32) {
    __syncthreads();
    gload16(a0, AsW);
    gload16(a1, AsW + 4096);
    gload16(b0, BsW);
    gload16(b1, BsW + 4096);
    a0 += 32; a1 += 32; b0 += 32; b1 += 32;
    __syncthreads();

    bf16x8 af[4], bfr[4];
#pragma unroll
    for (int i = 0; i < 4; ++i)
      af[i] = *(const bf16x8*)(As + (wm + 16 * i + fr) * 64 + sA);
#pragma unroll
    for (int j = 0; j < 4; ++j)
      bfr[j] = *(const bf16x8*)(Bs + (wn + 16 * j + fr) * 64 + sA);
#pragma unroll
    for (int i = 0; i < 4; ++i)
#pragma unroll
      for (int j = 0; j < 4; ++j)
        acc[i][j] = __builtin_amdgcn_mfma_f32_16x16x32_bf16(af[i], bfr[j],
                                                            acc[i][j], 0, 0, 0);
  }

  float* P = part + (size_t)blockIdx.z * M * N;
#pragma unroll
  for (int i = 0; i < 4; ++i) {
#pragma unroll
    for (int j = 0; j < 4; ++j) {
      int row0 = bm + wm + 16 * i + q * 4;
      int col = bn + wn + 16 * j + fr;
#pragma unroll
      for (int r = 0; r < 4; ++r)
        P[(size_t)(row0 + r) * N + col] = acc[i][j][r];
    }
  }
}

// ---------------------------------------------------------------------------
// out = act(sum_z part[z] + bias); optional fp32 and bf16 outputs.
// ---------------------------------------------------------------------------
__global__ __launch_bounds__(256) void reduce_kernel(
    const float* __restrict__ part, int S, int MN, int Nmask,
    const float* __restrict__ bias, int bias_n, int relu,
    float* __restrict__ outf, __bf16* __restrict__ outb) {
  int i4 = (blockIdx.x * 256 + threadIdx.x) * 4;
  if (i4 >= MN) return;
  f32x4 s = {0.f, 0.f, 0.f, 0.f};
  for (int z = 0; z < S; ++z) {
    f32x4 v = *(const f32x4*)&part[(size_t)z * MN + i4];
    s.x += v.x; s.y += v.y; s.z += v.z; s.w += v.w;
  }
  int col = i4 & Nmask;
  float r[4] = {s.x, s.y, s.z, s.w};
#pragma unroll
  for (int j = 0; j < 4; ++j) {
    float b = (col + j < bias_n) ? bias[col + j] : 0.0f;
    float v = r[j] + b;
    if (relu) v = fmaxf(v, 0.0f);
    r[j] = v;
  }
  if (outf) {
    f32x4 o = {r[0], r[1], r[2], r[3]};
    *(f32x4*)&outf[i4] = o;
  }
  if (outb) {
    bf16x4 o = {(__bf16)r[0], (__bf16)r[1], (__bf16)r[2], (__bf16)r[3]};
    *(bf16x4*)&outb[i4] = o;
  }
}

// ---------------------------------------------------------------------------
__global__ __launch_bounds__(256) void loc_head_kernel(
    const float* __restrict__ h2, const float* __restrict__ Wloc,
    const float* __restrict__ bloc, const int* __restrict__ label,
    float* __restrict__ loct) {
  int n = blockIdx.x;
  int d = threadIdx.x >> 6;
  int lane = threadIdx.x & 63;
  int lab = label[n];
  const float* h = h2 + (size_t)n * HID;
  const float* w = Wloc + (size_t)lab * 4 + d;
  float s = 0.0f;
#pragma unroll
  for (int i = 0; i < 16; ++i) {
    int k = lane + i * 64;
    s += h[k] * w[(size_t)k * (NUM_CLS * 4)];
  }
#pragma unroll
  for (int off = 32; off > 0; off >>= 1) s += __shfl_down(s, off);
  if (lane == 0) loct[n * 4 + d] = s + bloc[lab * 4 + d];
}

// ---------------------------------------------------------------------------
__global__ __launch_bounds__(512) void loss_kernel(
    const float* __restrict__ logits, const int* __restrict__ label,
    const float* __restrict__ loct, const float* __restrict__ loc,
    float* __restrict__ out) {
  int t = threadIdx.x;
  const float* row = logits + (size_t)t * 128;
  float m = -1e30f;
  for (int j = 0; j < NUM_CLS; ++j) m = fmaxf(m, row[j]);
  float se = 0.0f;
  for (int j = 0; j < NUM_CLS; ++j) se += expf(row[j] - m);
  float cl = (m + logf(se)) - row[label[t]];

  float a = fabsf(loct[t] - loc[t]);
  float bl = (a < 1.0f) ? 0.5f * a * a : a - 0.5f;

  float v = cl + bl;
#pragma unroll
  for (int off = 32; off > 0; off >>= 1) v += __shfl_down(v, off);

  __shared__ float red[8];
  if ((t & 63) == 0) red[t >> 6] = v;
  __syncthreads();
  if (t == 0) {
    float tot = 0.0f;
    for (int i = 0; i < 8; ++i) tot += red[i];
    out[0] = tot * (1.0f / (float)N_ROI);
  }
}

// ---------------------------------------------------------------------------
extern "C" void kernel_launch(void* const* d_in, const int* in_sizes, int n_in,
                              void* d_out, int out_size, void* d_ws, size_t ws_size,
                              hipStream_t stream) {
  const float* P2   = (const float*)d_in[0];
  const float* P3   = (const float*)d_in[1];
  const float* P4   = (const float*)d_in[2];
  const float* P5   = (const float*)d_in[3];
  const float* rois = (const float*)d_in[4];
  const int*   label= (const int*)d_in[5];
  const float* loc  = (const float*)d_in[6];
  const float* W1   = (const float*)d_in[7];
  const float* b1   = (const float*)d_in[8];
  const float* W2   = (const float*)d_in[9];
  const float* b2   = (const float*)d_in[10];
  const float* Wcls = (const float*)d_in[11];
  const float* bcls = (const float*)d_in[12];
  const float* Wloc = (const float*)d_in[13];
  const float* bloc = (const float*)d_in[14];
  float* out = (float*)d_out;

  char* w = (char*)d_ws;
  __bf16* xb  = (__bf16*)w;  w += (size_t)N_ROI * KDIM * 2;
  __bf16* W1t = (__bf16*)w;  w += (size_t)KDIM * HID * 2;
  __bf16* W2t = (__bf16*)w;  w += (size_t)HID * HID * 2;
  __bf16* WcT = (__bf16*)w;  w += (size_t)128 * HID * 2;
  __bf16* h1b = (__bf16*)w;  w += (size_t)N_ROI * HID * 2;
  __bf16* h2b = (__bf16*)w;  w += (size_t)N_ROI * HID * 2;
  float*  h2f = (float*)w;   w += (size_t)N_ROI * HID * 4;
  float*  logits = (float*)w; w += (size_t)N_ROI * 128 * 4;
  float*  loct = (float*)w;  w += (size_t)N_ROI * 4;
  float*  part = (float*)w;

  transpose_to_bf16_64<<<dim3(HID / 64, KDIM / 64), 256, 0, stream>>>(W1, W1t,
                                                                      KDIM, HID);
  transpose_to_bf16_64<<<dim3(HID / 64, HID / 64), 256, 0, stream>>>(W2, W2t,
                                                                     HID, HID);
  transpose_pad_cls<<<dim3(16, 2), 256, 0, stream>>>(Wcls, WcT);
  roi_align_kernel<<<dim3(N_ROI, 16), 256, 0, stream>>>(P2, P3, P4, P5, rois,
                                                        xb);

  // FC1: [512,12544]@[12544,1024], split-K 16 (chunk 800; last 544)
  mfma_gemm128<<<dim3(HID / 128, N_ROI / 128, 16), 256, 0, stream>>>(
      xb, W1t, part, N_ROI, HID, KDIM, 800);
  reduce_kernel<<<(N_ROI * HID) / 1024, 256, 0, stream>>>(
      part, 16, N_ROI * HID, HID - 1, b1, HID, 1, nullptr, h1b);

  // FC2: [512,1024]@[1024,1024], split-K 8 (chunk 128)
  mfma_gemm128<<<dim3(HID / 128, N_ROI / 128, 8), 256, 0, stream>>>(
      h1b, W2t, part, N_ROI, HID, HID, 128);
  reduce_kernel<<<(N_ROI * HID) / 1024, 256, 0, stream>>>(
      part, 8, N_ROI * HID, HID - 1, b2, HID, 1, h2f, h2b);

  // cls head: [512,1024]@[1024,128pad], split-K 4 (chunk 256)
  mfma_gemm128<<<dim3(1, N_ROI / 128, 4), 256, 0, stream>>>(
      h2b, WcT, part, N_ROI, 128, HID, 256);
  reduce_kernel<<<(N_ROI * 128) / 1024, 256, 0, stream>>>(
      part, 4, N_ROI * 128, 127, bcls, NUM_CLS, 0, logits, nullptr);

  loc_head_kernel<<<N_POS, 256, 0, stream>>>(h2f, Wloc, bloc, label, loct);
  loss_kernel<<<1, 512, 0, stream>>>(logits, label, loct, loc, out);
}

// Round 7
// 284.946 us; speedup vs baseline: 1.2712x; 1.0272x over previous
//
#include <hip/hip_runtime.h>
#include <hip/hip_bf16.h>
#include <math.h>

#define N_ROI 512
#define N_POS 128
#define NUM_CLS 81
#define KDIM 12544          // 256 ch * 7 * 7
#define HID 1024

typedef __bf16 bf16x8 __attribute__((ext_vector_type(8)));
typedef __bf16 bf16x4 __attribute__((ext_vector_type(4)));
typedef float f32x4 __attribute__((ext_vector_type(4)));

__device__ inline void gload16(const void* g, void* lds) {
  __builtin_amdgcn_global_load_lds(
      (const __attribute__((address_space(1))) void*)g,
      (__attribute__((address_space(3))) void*)lds, 16, 0, 0);
}

// ---------------------------------------------------------------------------
// Fused prep kernel, 1D grid of 7520 blocks:
//   [0,4096)        roi_align: n = bid&511, group = bid>>9 (8 groups of 32ch;
//                   wave = 8 consecutive channels; 64 float2 loads batched)
//   [4096,7232)     W1 transpose->bf16 [12544][1024] -> [1024][12544]
//   [7232,7488)     W2 transpose->bf16
//   [7488,7520)     Wcls transpose+pad -> [128][1024]
// roi blocks come first so the BW-bound transposes backfill CUs while the
// latency-bound roi gathers drain.
// ---------------------------------------------------------------------------
__global__ __launch_bounds__(256, 2) void prep_kernel(
    const float* __restrict__ P2, const float* __restrict__ P3,
    const float* __restrict__ P4, const float* __restrict__ P5,
    const float* __restrict__ rois, __bf16* __restrict__ xout,
    const float* __restrict__ W1, __bf16* __restrict__ W1t,
    const float* __restrict__ W2, __bf16* __restrict__ W2t,
    const float* __restrict__ Wcls, __bf16* __restrict__ WcT) {
  __shared__ float tile[64][65];          // transposes
  __shared__ int    gxo[14];              // roi: min(x0,W-2)*4
  __shared__ float2 gxf[14];              // roi: {lx', vx}
  __shared__ int2   gyi[14];              // roi: {y0*W*4, y1*W*4}
  __shared__ float2 gyf[14];              // roi: {ly, vy}
  __shared__ int    s_lvl, s_HWb;

  int bid = blockIdx.x;
  int t = threadIdx.x;

  if (bid < 4096) {
    // ---------------- ROI align ----------------
    int n = bid & 511;
    int grp = bid >> 9;

    float rx1 = rois[n * 4 + 0], ry1 = rois[n * 4 + 1];
    float rx2 = rois[n * 4 + 2], ry2 = rois[n * 4 + 3];
    float area = (rx2 - rx1 + 1.0f) * (ry2 - ry1 + 1.0f);
    float lf = floorf(4.0f + log2f(sqrtf(area) / 224.0f));
    lf = fminf(fmaxf(lf, 2.0f), 5.0f);
    int lvl = (int)lf - 2;

    const float scales[4] = {0.25f, 0.125f, 0.0625f, 0.03125f};
    const int   Hs[4] = {200, 100, 50, 25};
    const int   Ws[4] = {256, 128, 64, 32};
    float sc = scales[lvl];
    int H = Hs[lvl], W = Ws[lvl];

    float bx1 = rx1 * sc, by1 = ry1 * sc;
    float bw = fmaxf(rx2 * sc - bx1, 1.0f) * (1.0f / 7.0f);
    float bh = fmaxf(ry2 * sc - by1, 1.0f) * (1.0f / 7.0f);

    if (t < 14) {
      int i = t >> 1, j = t & 1;
      float g = (float)i + 0.25f + 0.5f * (float)j;
      float px = bx1 + g * bw;
      float vx = (px > -1.0f && px < (float)W) ? 1.0f : 0.0f;
      float xx = fminf(fmaxf(px, 0.0f), (float)(W - 1));
      float x0f = floorf(xx);
      int x0 = (int)x0f;
      int xa = min(x0, W - 2);
      gxo[t] = xa * 4;
      gxf[t] = make_float2((x0 > xa) ? 1.0f : (xx - x0f), vx);
      if (t == 0) { s_lvl = lvl; s_HWb = H * W * 4; }
    } else if (t >= 64 && t < 78) {
      int s = t - 64;
      int i = s >> 1, j = s & 1;
      float g = (float)i + 0.25f + 0.5f * (float)j;
      float py = by1 + g * bh;
      float vy = (py > -1.0f && py < (float)H) ? 1.0f : 0.0f;
      float yy = fminf(fmaxf(py, 0.0f), (float)(H - 1));
      float y0f = floorf(yy);
      int y0 = (int)y0f;
      int y1 = min(y0 + 1, H - 1);
      gyi[s] = make_int2(y0 * W * 4, y1 * W * 4);
      gyf[s] = make_float2(yy - y0f, vy);
    }
    __syncthreads();

    int lvl_s = __builtin_amdgcn_readfirstlane(s_lvl);
    const char* base = (const char*)(lvl_s == 0 ? P2 : lvl_s == 1 ? P3
                                     : lvl_s == 2 ? P4 : P5);
    int HWb = s_HWb;

    int wave = t >> 6, lane = t & 63;
    if (lane >= 49) return;

    int oh = (lane * 37) >> 8;
    int ow = lane - oh * 7;

    int2   xo = *(const int2*)&gxo[2 * ow];
    float4 xf = *(const float4*)&gxf[2 * ow];
    int4   yi = *(const int4*)&gyi[2 * oh];
    float4 yf = *(const float4*)&gyf[2 * oh];

    int off[8];
    off[0] = yi.x + xo.x; off[1] = yi.y + xo.x;
    off[2] = yi.x + xo.y; off[3] = yi.y + xo.y;
    off[4] = yi.z + xo.x; off[5] = yi.w + xo.x;
    off[6] = yi.z + xo.y; off[7] = yi.w + xo.y;

    float w00 = yf.y * xf.y, w01 = yf.y * xf.w;
    float w10 = yf.w * xf.y, w11 = yf.w * xf.w;

    int c0 = grp * 32 + wave * 8;
    const char* bc0 = base + (size_t)c0 * HWb;

    float2 g[8][8];
#pragma unroll
    for (int ch = 0; ch < 8; ++ch) {
      const char* bcc = bc0 + (size_t)ch * HWb;
#pragma unroll
      for (int l = 0; l < 8; ++l)
        g[ch][l] = *(const float2*)(bcc + off[l]);
    }

    __bf16* outp = xout + (size_t)n * KDIM + (size_t)c0 * 49 + lane;
#pragma unroll
    for (int ch = 0; ch < 8; ++ch) {
      float fa, fb, s = 0.0f;
      fa = g[ch][0].x + xf.x * (g[ch][0].y - g[ch][0].x);
      fb = g[ch][1].x + xf.x * (g[ch][1].y - g[ch][1].x);
      s += (fa + yf.x * (fb - fa)) * w00;
      fa = g[ch][2].x + xf.z * (g[ch][2].y - g[ch][2].x);
      fb = g[ch][3].x + xf.z * (g[ch][3].y - g[ch][3].x);
      s += (fa + yf.x * (fb - fa)) * w01;
      fa = g[ch][4].x + xf.x * (g[ch][4].y - g[ch][4].x);
      fb = g[ch][5].x + xf.x * (g[ch][5].y - g[ch][5].x);
      s += (fa + yf.z * (fb - fa)) * w10;
      fa = g[ch][6].x + xf.z * (g[ch][6].y - g[ch][6].x);
      fb = g[ch][7].x + xf.z * (g[ch][7].y - g[ch][7].x);
      s += (fa + yf.z * (fb - fa)) * w11;
      outp[ch * 49] = (__bf16)(s * 0.25f);
    }
    return;
  }

  // ---------------- transposes ----------------
  const float* src;
  __bf16* dst;
  int R, C, bcb, brb;
  bool pad_cls = false;
  if (bid < 4096 + 3136) {
    int id = bid - 4096;
    src = W1; dst = W1t; R = KDIM; C = HID;
    bcb = (id & 15) * 64; brb = (id >> 4) * 64;
  } else if (bid < 4096 + 3136 + 256) {
    int id = bid - (4096 + 3136);
    src = W2; dst = W2t; R = HID; C = HID;
    bcb = (id & 15) * 64; brb = (id >> 4) * 64;
  } else {
    int id = bid - (4096 + 3136 + 256);
    src = Wcls; dst = WcT; R = HID; C = 128;
    bcb = (id >> 4) * 64; brb = (id & 15) * 64;
    pad_cls = true;
  }

  int rr = t >> 4, c4 = (t & 15) * 4;
  if (!pad_cls) {
#pragma unroll
    for (int p = 0; p < 4; ++p) {
      int r = p * 16 + rr;
      f32x4 v = *(const f32x4*)&src[(size_t)(brb + r) * C + bcb + c4];
      tile[r][c4] = v.x; tile[r][c4 + 1] = v.y;
      tile[r][c4 + 2] = v.z; tile[r][c4 + 3] = v.w;
    }
  } else {
#pragma unroll
    for (int p = 0; p < 4; ++p) {
      int r = p * 16 + rr;
#pragma unroll
      for (int i = 0; i < 4; ++i) {
        int j = bcb + c4 + i;
        tile[r][c4 + i] =
            (j < NUM_CLS) ? src[(size_t)(brb + r) * NUM_CLS + j] : 0.0f;
      }
    }
  }
  __syncthreads();
#pragma unroll
  for (int p = 0; p < 2; ++p) {
    int group = t + 256 * p;
    int c = group >> 3;
    int r0 = (group & 7) * 8;
    bf16x8 o;
#pragma unroll
    for (int j = 0; j < 8; ++j) o[j] = (__bf16)tile[r0 + j][c];
    *(bf16x8*)&dst[(size_t)(bcb + c) * R + brb + r0] = o;
  }
}

// ---------------------------------------------------------------------------
// m97-style bf16 MFMA GEMM with split-K partials. Block tile 128x128, BK=32,
// 4 waves x (64x64). global_load_lds width=16 with chunk swizzle.
// ---------------------------------------------------------------------------
__global__ __launch_bounds__(256, 2) void mfma_gemm128(
    const __bf16* __restrict__ A, const __bf16* __restrict__ Bt,
    float* __restrict__ part, int M, int N, int K, int chunk) {
  __shared__ __align__(16) unsigned char smem[16384];
  unsigned char* As = smem;
  unsigned char* Bs = smem + 8192;

  int t = threadIdx.x;
  int wave = t >> 6;
  int lane = t & 63;
  int fr = lane & 15, q = lane >> 4;
  int bm = blockIdx.y * 128, bn = blockIdx.x * 128;
  int wm = (wave >> 1) * 64, wn = (wave & 1) * 64;

  int kbeg = blockIdx.z * chunk;
  int kend = min(K, kbeg + chunk);

  int qsrc = ((t & 3) - ((t >> 3) & 3)) & 3;
  const __bf16* a0 = A + (size_t)(bm + (t >> 2)) * K + kbeg + qsrc * 8;
  const __bf16* a1 = a0 + (size_t)64 * K;
  const __bf16* b0 = Bt + (size_t)(bn + (t >> 2)) * K + kbeg + qsrc * 8;
  const __bf16* b1 = b0 + (size_t)64 * K;
  unsigned char* AsW = As + wave * 1024;
  unsigned char* BsW = Bs + wave * 1024;

  int sA = ((q + (fr >> 1)) & 3) * 16;

  f32x4 acc[4][4];
#pragma unroll
  for (int i = 0; i < 4; ++i)
#pragma unroll
    for (int j = 0; j < 4; ++j) acc[i][j] = (f32x4){0.f, 0.f, 0.f, 0.f};

  for (int k0 = kbeg; k0 < kend; k0 += 32) {
    __syncthreads();
    gload16(a0, AsW);
    gload16(a1, AsW + 4096);
    gload16(b0, BsW);
    gload16(b1, BsW + 4096);
    a0 += 32; a1 += 32; b0 += 32; b1 += 32;
    __syncthreads();

    bf16x8 af[4], bfr[4];
#pragma unroll
    for (int i = 0; i < 4; ++i)
      af[i] = *(const bf16x8*)(As + (wm + 16 * i + fr) * 64 + sA);
#pragma unroll
    for (int j = 0; j < 4; ++j)
      bfr[j] = *(const bf16x8*)(Bs + (wn + 16 * j + fr) * 64 + sA);
#pragma unroll
    for (int i = 0; i < 4; ++i)
#pragma unroll
      for (int j = 0; j < 4; ++j)
        acc[i][j] = __builtin_amdgcn_mfma_f32_16x16x32_bf16(af[i], bfr[j],
                                                            acc[i][j], 0, 0, 0);
  }

  float* P = part + (size_t)blockIdx.z * M * N;
#pragma unroll
  for (int i = 0; i < 4; ++i) {
#pragma unroll
    for (int j = 0; j < 4; ++j) {
      int row0 = bm + wm + 16 * i + q * 4;
      int col = bn + wn + 16 * j + fr;
#pragma unroll
      for (int r = 0; r < 4; ++r)
        P[(size_t)(row0 + r) * N + col] = acc[i][j][r];
    }
  }
}

// ---------------------------------------------------------------------------
// out = act(sum_z part[z] + bias); optional fp32 and bf16 outputs.
// ---------------------------------------------------------------------------
__global__ __launch_bounds__(256) void reduce_kernel(
    const float* __restrict__ part, int S, int MN, int Nmask,
    const float* __restrict__ bias, int bias_n, int relu,
    float* __restrict__ outf, __bf16* __restrict__ outb) {
  int i4 = (blockIdx.x * 256 + threadIdx.x) * 4;
  if (i4 >= MN) return;
  f32x4 s = {0.f, 0.f, 0.f, 0.f};
  for (int z = 0; z < S; ++z) {
    f32x4 v = *(const f32x4*)&part[(size_t)z * MN + i4];
    s.x += v.x; s.y += v.y; s.z += v.z; s.w += v.w;
  }
  int col = i4 & Nmask;
  float r[4] = {s.x, s.y, s.z, s.w};
#pragma unroll
  for (int j = 0; j < 4; ++j) {
    float b = (col + j < bias_n) ? bias[col + j] : 0.0f;
    float v = r[j] + b;
    if (relu) v = fmaxf(v, 0.0f);
    r[j] = v;
  }
  if (outf) {
    f32x4 o = {r[0], r[1], r[2], r[3]};
    *(f32x4*)&outf[i4] = o;
  }
  if (outb) {
    bf16x4 o = {(__bf16)r[0], (__bf16)r[1], (__bf16)r[2], (__bf16)r[3]};
    *(bf16x4*)&outb[i4] = o;
  }
}

// ---------------------------------------------------------------------------
__global__ __launch_bounds__(256) void loc_head_kernel(
    const float* __restrict__ h2, const float* __restrict__ Wloc,
    const float* __restrict__ bloc, const int* __restrict__ label,
    float* __restrict__ loct) {
  int n = blockIdx.x;
  int d = threadIdx.x >> 6;
  int lane = threadIdx.x & 63;
  int lab = label[n];
  const float* h = h2 + (size_t)n * HID;
  const float* w = Wloc + (size_t)lab * 4 + d;
  float s = 0.0f;
#pragma unroll
  for (int i = 0; i < 16; ++i) {
    int k = lane + i * 64;
    s += h[k] * w[(size_t)k * (NUM_CLS * 4)];
  }
#pragma unroll
  for (int off = 32; off > 0; off >>= 1) s += __shfl_down(s, off);
  if (lane == 0) loct[n * 4 + d] = s + bloc[lab * 4 + d];
}

// ---------------------------------------------------------------------------
__global__ __launch_bounds__(512) void loss_kernel(
    const float* __restrict__ logits, const int* __restrict__ label,
    const float* __restrict__ loct, const float* __restrict__ loc,
    float* __restrict__ out) {
  int t = threadIdx.x;
  const float* row = logits + (size_t)t * 128;
  float m = -1e30f;
  for (int j = 0; j < NUM_CLS; ++j) m = fmaxf(m, row[j]);
  float se = 0.0f;
  for (int j = 0; j < NUM_CLS; ++j) se += expf(row[j] - m);
  float cl = (m + logf(se)) - row[label[t]];

  float a = fabsf(loct[t] - loc[t]);
  float bl = (a < 1.0f) ? 0.5f * a * a : a - 0.5f;

  float v = cl + bl;
#pragma unroll
  for (int off = 32; off > 0; off >>= 1) v += __shfl_down(v, off);

  __shared__ float red[8];
  if ((t & 63) == 0) red[t >> 6] = v;
  __syncthreads();
  if (t == 0) {
    float tot = 0.0f;
    for (int i = 0; i < 8; ++i) tot += red[i];
    out[0] = tot * (1.0f / (float)N_ROI);
  }
}

// ---------------------------------------------------------------------------
extern "C" void kernel_launch(void* const* d_in, const int* in_sizes, int n_in,
                              void* d_out, int out_size, void* d_ws, size_t ws_size,
                              hipStream_t stream) {
  const float* P2   = (const float*)d_in[0];
  const float* P3   = (const float*)d_in[1];
  const float* P4   = (const float*)d_in[2];
  const float* P5   = (const float*)d_in[3];
  const float* rois = (const float*)d_in[4];
  const int*   label= (const int*)d_in[5];
  const float* loc  = (const float*)d_in[6];
  const float* W1   = (const float*)d_in[7];
  const float* b1   = (const float*)d_in[8];
  const float* W2   = (const float*)d_in[9];
  const float* b2   = (const float*)d_in[10];
  const float* Wcls = (const float*)d_in[11];
  const float* bcls = (const float*)d_in[12];
  const float* Wloc = (const float*)d_in[13];
  const float* bloc = (const float*)d_in[14];
  float* out = (float*)d_out;

  char* w = (char*)d_ws;
  __bf16* xb  = (__bf16*)w;  w += (size_t)N_ROI * KDIM * 2;
  __bf16* W1t = (__bf16*)w;  w += (size_t)KDIM * HID * 2;
  __bf16* W2t = (__bf16*)w;  w += (size_t)HID * HID * 2;
  __bf16* WcT = (__bf16*)w;  w += (size_t)128 * HID * 2;
  __bf16* h1b = (__bf16*)w;  w += (size_t)N_ROI * HID * 2;
  __bf16* h2b = (__bf16*)w;  w += (size_t)N_ROI * HID * 2;
  float*  h2f = (float*)w;   w += (size_t)N_ROI * HID * 4;
  float*  logits = (float*)w; w += (size_t)N_ROI * 128 * 4;
  float*  loct = (float*)w;  w += (size_t)N_ROI * 4;
  float*  part = (float*)w;

  // fused: roi_align (4096 blocks, first) + W1/W2/Wcls transposes
  prep_kernel<<<4096 + 3136 + 256 + 32, 256, 0, stream>>>(
      P2, P3, P4, P5, rois, xb, W1, W1t, W2, W2t, Wcls, WcT);

  // FC1: [512,12544]@[12544,1024], split-K 16 (chunk 800; last 544)
  mfma_gemm128<<<dim3(HID / 128, N_ROI / 128, 16), 256, 0, stream>>>(
      xb, W1t, part, N_ROI, HID, KDIM, 800);
  reduce_kernel<<<(N_ROI * HID) / 1024, 256, 0, stream>>>(
      part, 16, N_ROI * HID, HID - 1, b1, HID, 1, nullptr, h1b);

  // FC2: [512,1024]@[1024,1024], split-K 8 (chunk 128)
  mfma_gemm128<<<dim3(HID / 128, N_ROI / 128, 8), 256, 0, stream>>>(
      h1b, W2t, part, N_ROI, HID, HID, 128);
  reduce_kernel<<<(N_ROI * HID) / 1024, 256, 0, stream>>>(
      part, 8, N_ROI * HID, HID - 1, b2, HID, 1, h2f, h2b);

  // cls head: [512,1024]@[1024,128pad], split-K 8 (chunk 128)
  mfma_gemm128<<<dim3(1, N_ROI / 128, 8), 256, 0, stream>>>(
      h2b, WcT, part, N_ROI, 128, HID, 128);
  reduce_kernel<<<(N_ROI * 128) / 1024, 256, 0, stream>>>(
      part, 8, N_ROI * 128, 127, bcls, NUM_CLS, 0, logits, nullptr);

  loc_head_kernel<<<N_POS, 256, 0, stream>>>(h2f, Wloc, bloc, label, loct);
  loss_kernel<<<1, 512, 0, stream>>>(logits, label, loct, loc, out);
}